// Round 5
// baseline (816.386 us; speedup 1.0000x reference)
//
#include <hip/hip_runtime.h>

typedef __bf16 bf16_t;
typedef bf16_t bf16x8 __attribute__((ext_vector_type(8)));
typedef bf16_t bf16x4 __attribute__((ext_vector_type(4)));
typedef float  f32x4  __attribute__((ext_vector_type(4)));

#define DEVFN __device__ __forceinline__

constexpr int BATCH = 256;
constexpr int DDIM  = 512;
constexpr int HDIM  = 2048;
constexpr int MNODE = 64;
constexpr int NC    = 32;
constexpr int NITER = 12;
constexpr int PT    = 10;
constexpr int CROWS = BATCH * NC;  // 8192 coefficient rows

DEVFN float fast_tanh(float x) {
  float e = __builtin_amdgcn_exp2f(x * 2.8853900817779268f);
  return 1.0f - 2.0f * __builtin_amdgcn_rcpf(e + 1.0f);
}

DEVFN void gload_lds16(const void* g, void* l) {
  __builtin_amdgcn_global_load_lds(
      (__attribute__((address_space(1))) void*)(g),
      (__attribute__((address_space(3))) void*)(l), 16, 0, 0);
}

DEVFN f32x4 mfma16(bf16x8 a, bf16x8 b, f32x4 c) {
  return __builtin_amdgcn_mfma_f32_16x16x32_bf16(a, b, c, 0, 0, 0);
}

// ---- 128B-row (BK=64) staging/reads: 8-slot XOR swizzle -------------------
DEVFN void stage256(const bf16_t* g, int ldK, char* buf, int tid, int j) {
  const int t = j * 256 + tid;
  const int row = t >> 3;
  const int k = ((tid & 7) ^ (row & 7)) * 8;
  gload_lds16(g + (size_t)row * ldK + k, buf + t * 16);
}
DEVFN bf16x8 frag(const void* buf, int row, int ks, int lg) {
  const int byte = row * 128 + ((ks * 64 + lg * 16) ^ ((row & 7) << 4));
  return *(const bf16x8*)((const char*)buf + byte);
}

// ---- 64B-row (BK=32) staging/reads: 4-slot XOR swizzle --------------------
DEVFN void stage32(const bf16_t* g, int ldK, char* buf, int tid, int j) {
  const int t = j * 256 + tid;
  const int row = t >> 2;
  const int k = (((t & 3) ^ (row & 3)) * 8);
  gload_lds16(g + (size_t)row * ldK + k, buf + t * 16);
}
DEVFN bf16x8 frag32(const void* buf, int row, int lg) {
  const int byte = row * 64 + ((lg * 16) ^ ((row & 3) << 4));
  return *(const bf16x8*)((const char*)buf + byte);
}

// ---------------------------------------------------------------------------
// Prep: PhiT[64m][32n] (bf16), M2[32n'][64m] = A32@psi (bf16),
// PS[16p][32n] (f32, zero for p>=10), a2s[32] = rowsum(M2) (f32).
// ---------------------------------------------------------------------------
__global__ __launch_bounds__(256) void prep_matrices(
    const float* __restrict__ tspan, bf16_t* __restrict__ PhiT,
    bf16_t* __restrict__ M2, float* __restrict__ PS,
    float* __restrict__ a2s) {
  __shared__ float sphi[NC][MNODE];
  __shared__ float spsi[NC][MNODE];
  __shared__ float sA32[NC][NC];
  __shared__ float sAP[NC][MNODE];
  __shared__ float sphis[NC][PT];

  const int tid = threadIdx.x;
  const float t0 = tspan[0], t1 = tspan[PT - 1];
  const float half = 0.5f * (t1 - t0);
  const float pi = 3.14159265358979323846f;

  for (int i = tid; i < NC * MNODE; i += 256) {
    int n = i >> 6, m = i & 63;
    float th = pi * (float)m / 63.0f;
    float ph = cosf((float)n * th);
    sphi[n][m] = ph;
    float w = (m == 0 || m == 63) ? 0.5f : 1.0f;
    spsi[n][m] = ph * w * (2.0f / 63.0f) * (n == 0 ? 0.5f : 1.0f);
  }
  for (int i = tid; i < NC * NC; i += 256) {
    int j = i >> 5, q = i & 31;
    float v = 0.f;
    for (int k = 1; k < NC; ++k) {
      float dk = half / (2.0f * (float)k);
      float dval = 0.f;
      if (q == k - 1) dval += dk;
      if (q == k + 1) dval -= dk;
      float pj = (j == 0) ? ((k & 1) ? 1.0f : -1.0f) : ((j == k) ? 1.0f : 0.0f);
      v += pj * dval;
    }
    sA32[j][q] = v;
  }
  for (int i = tid; i < NC * PT; i += 256) {
    int n = i / PT, p = i % PT;
    float tau = -1.0f + 2.0f * (tspan[p] - t0) / (t1 - t0);
    tau = fminf(1.0f, fmaxf(-1.0f, tau));
    sphis[n][p] = cosf((float)n * acosf(tau));
  }
  __syncthreads();
  for (int i = tid; i < NC * MNODE; i += 256) {
    int n = i >> 6, m = i & 63;
    float v = 0.f;
    for (int q = 0; q < NC; ++q) v += sA32[n][q] * spsi[q][m];
    sAP[n][m] = v;
  }
  __syncthreads();
  for (int i = tid; i < MNODE * NC; i += 256) {  // PhiT[m][n]
    int m = i >> 5, n = i & 31;
    PhiT[i] = (bf16_t)sphi[n][m];
  }
  for (int i = tid; i < NC * MNODE; i += 256) {  // M2[n'][m]
    int n = i >> 6, m = i & 63;
    M2[i] = (bf16_t)sAP[n][m];
  }
  for (int i = tid; i < 16 * NC; i += 256) {     // PS[p][n]
    int p = i >> 5, n = i & 31;
    PS[i] = (p < PT) ? sphis[n][p] : 0.f;
  }
  if (tid < NC) {
    float s = 0.f;
    for (int m = 0; m < MNODE; ++m) s += sAP[tid][m];
    a2s[tid] = s;
  }
}

// Transpose f32 [R][C] -> bf16 [C][R]
__global__ void transpose_bf16(const float* __restrict__ src,
                               bf16_t* __restrict__ dst, int R, int C) {
  __shared__ float tile[32][33];
  const int bx = blockIdx.x * 32, by = blockIdx.y * 32;
  const int tx = threadIdx.x, ty = threadIdx.y;
#pragma unroll
  for (int i = 0; i < 32; i += 8)
    tile[ty + i][tx] = src[(size_t)(by + ty + i) * C + (bx + tx)];
  __syncthreads();
#pragma unroll
  for (int i = 0; i < 32; i += 8)
    dst[(size_t)(bx + ty + i) * R + (by + tx)] = (bf16_t)tile[tx][ty + i];
}

// Bc[b*32+n][d] = (n==0) ? y0[b][d] : 0
__global__ void init_Bc(const float* __restrict__ y0, bf16_t* __restrict__ Bc) {
  size_t i = (size_t)blockIdx.x * 256 + threadIdx.x;  // < CROWS*DDIM
  int d = (int)(i & 511);
  int row = (int)(i >> 9);
  int n = row & 31, b = row >> 5;
  Bc[i] = (n == 0) ? (bf16_t)y0[((size_t)b << 9) + d] : (bf16_t)0.f;
}

// ---------------------------------------------------------------------------
// Kernel A (mlp_front): G = Bc@W1^T, 128x128 tile, BK=32 dbuf, counted vmcnt,
// 40KB static LDS -> 3-4 blocks/CU (m97 regime).  Epilogue per batch:
// E^T = G^T@PhiT + b1; H = tanh(E); C2 = M2@H -> global [CROWS x 2048] bf16.
// ---------------------------------------------------------------------------
__global__ __launch_bounds__(256, 3) void mlp_front(
    const bf16_t* __restrict__ Bc, const bf16_t* __restrict__ W1t,
    const float* __restrict__ b1, const bf16_t* __restrict__ PhiT,
    const bf16_t* __restrict__ M2, bf16_t* __restrict__ C2) {
  // main: As dbuf [0,16K), Bs dbuf [16K,32K)
  // epi : Gs [0,8K), Hs [8K,24K)
  // const: PhiTs [32K,36K), M2s [36K,40K)
  __shared__ alignas(16) char lds[40960];
  char* PhiTs = lds + 32768;
  char* M2s = lds + 36864;

  const int tid = threadIdx.x;
  const int wid = tid >> 6, lane = tid & 63;
  const int lr = lane & 15, lg = lane >> 4;
  const int id = blockIdx.x, nwg = gridDim.x;
  const int swz = (id & 7) * (nwg >> 3) + (id >> 3);  // XCD-contiguous
  const int bx = swz & 15, by = swz >> 4;  // 16 col-blocks, 64 row-blocks
  const int row0 = by * 128, col0 = bx * 128;
  const int wr = (wid >> 1) * 64, wc = (wid & 1) * 64;

  const bf16_t* Ag = Bc + (size_t)row0 * DDIM;
  const bf16_t* Bg = W1t + (size_t)col0 * DDIM;

  // prologue: constants (oldest), then K-tiles 0 and 1
  {
    int rowp = tid >> 2;
    int kp = ((tid & 3) ^ (rowp & 3)) * 8;
    gload_lds16(PhiT + rowp * 32 + kp, PhiTs + tid * 16);
    int rowm = tid >> 3;
    int km = ((tid & 7) ^ (rowm & 7)) * 8;
    gload_lds16(M2 + rowm * 64 + km, M2s + tid * 16);
  }
  stage32(Ag, DDIM, lds, tid, 0);
  stage32(Ag, DDIM, lds, tid, 1);
  stage32(Bg, DDIM, lds + 16384, tid, 0);
  stage32(Bg, DDIM, lds + 16384, tid, 1);

  const f32x4 fz = {0.f, 0.f, 0.f, 0.f};
  f32x4 acc[4][4];
#pragma unroll
  for (int i = 0; i < 4; ++i)
#pragma unroll
    for (int j = 0; j < 4; ++j) acc[i][j] = fz;

  constexpr int nk = DDIM / 32;  // 16
  for (int kt = 0; kt < nk; ++kt) {
    const int cur = kt & 1;
    if (kt + 1 < nk) {
      char* A2 = lds + (cur ^ 1) * 8192;
      char* B2 = lds + 16384 + (cur ^ 1) * 8192;
      stage32(Ag + (kt + 1) * 32, DDIM, A2, tid, 0);
      stage32(Ag + (kt + 1) * 32, DDIM, A2, tid, 1);
      stage32(Bg + (kt + 1) * 32, DDIM, B2, tid, 0);
      stage32(Bg + (kt + 1) * 32, DDIM, B2, tid, 1);
      asm volatile("s_waitcnt vmcnt(4)" ::: "memory");  // tile kt landed
    } else {
      asm volatile("s_waitcnt vmcnt(0)" ::: "memory");
    }
    __builtin_amdgcn_s_barrier();
    __builtin_amdgcn_sched_barrier(0);
    const char* Ab = lds + cur * 8192;
    const char* Bb = lds + 16384 + cur * 8192;
    bf16x8 af[4], bfv[4];
#pragma unroll
    for (int mi = 0; mi < 4; ++mi) af[mi] = frag32(Ab, wr + mi * 16 + lr, lg);
#pragma unroll
    for (int ni = 0; ni < 4; ++ni) bfv[ni] = frag32(Bb, wc + ni * 16 + lr, lg);
#pragma unroll
    for (int mi = 0; mi < 4; ++mi)
#pragma unroll
      for (int ni = 0; ni < 4; ++ni)
        acc[mi][ni] = mfma16(af[mi], bfv[ni], acc[mi][ni]);
    __builtin_amdgcn_sched_barrier(0);
    __builtin_amdgcn_s_barrier();
  }

  // ---- epilogue: per-batch G staging (Gs 8KB), E/H/C2 ----
  char* Gs = lds;
  char* Hs = lds + 8192;
  const float* b1g = b1 + col0;
  const int bg0 = row0 >> 5;

  // write G slice for batch 0
#pragma unroll
  for (int b0 = 0; b0 < 1; ++b0) {
    if ((wid >> 1) == 0) {
#pragma unroll
      for (int mil = 0; mil < 2; ++mil) {
        const int mi = mil;  // b=0: mi-pair {0,1}
        const int n0 = mil * 16 + lg * 4;
#pragma unroll
        for (int ni = 0; ni < 4; ++ni) {
          const int h = wc + ni * 16 + lr;
          bf16x4 pk;
#pragma unroll
          for (int r = 0; r < 4; ++r) pk[r] = (bf16_t)acc[mi][ni][r];
          *(bf16x4*)(Gs + h * 64 + ((n0 * 2) ^ ((h & 3) << 4))) = pk;
        }
      }
    }
  }
  __syncthreads();

  // hoisted operand frags (batch-invariant)
  bf16x8 pb[4];
#pragma unroll
  for (int ni = 0; ni < 4; ++ni) {
    const int m = ni * 16 + lr;
    pb[ni] = *(const bf16x8*)(PhiTs + m * 64 + ((lg * 16) ^ ((m & 3) << 4)));
  }
  bf16x8 am[2][2];
#pragma unroll
  for (int mi = 0; mi < 2; ++mi)
#pragma unroll
    for (int ks = 0; ks < 2; ++ks) am[mi][ks] = frag(M2s, mi * 16 + lr, ks, lg);

#pragma unroll
  for (int b = 0; b < 4; ++b) {
    // E^T slice: wave wid -> h rows [wid*32, +32), K = 32 coeffs
    f32x4 e[2][4];
#pragma unroll
    for (int i = 0; i < 2; ++i)
#pragma unroll
      for (int j = 0; j < 4; ++j) e[i][j] = fz;
#pragma unroll
    for (int mi2 = 0; mi2 < 2; ++mi2) {
      const int h = wid * 32 + mi2 * 16 + lr;
      bf16x8 ga =
          *(const bf16x8*)(Gs + h * 64 + ((lg * 16) ^ ((h & 3) << 4)));
#pragma unroll
      for (int ni = 0; ni < 4; ++ni) e[mi2][ni] = mfma16(ga, pb[ni], e[mi2][ni]);
    }
    // H = tanh(E + b1) -> Hs [h][m] swizzled
#pragma unroll
    for (int mi2 = 0; mi2 < 2; ++mi2)
#pragma unroll
      for (int ni = 0; ni < 4; ++ni)
#pragma unroll
        for (int r = 0; r < 4; ++r) {
          const int h = wid * 32 + mi2 * 16 + lg * 4 + r;
          const int m = ni * 16 + lr;
          float v = fast_tanh(e[mi2][ni][r] + b1g[h]);
          *(bf16_t*)(Hs + h * 128 + ((m * 2) ^ ((h & 7) << 4))) = (bf16_t)v;
        }
    __syncthreads();
    // C2 = M2 @ H : wave wid -> h cols [wid*32, +32), K = 64 nodes
    f32x4 c2a[2][2];
#pragma unroll
    for (int i = 0; i < 2; ++i)
#pragma unroll
      for (int j = 0; j < 2; ++j) c2a[i][j] = fz;
#pragma unroll
    for (int ks = 0; ks < 2; ++ks) {
      bf16x8 hb[2];
#pragma unroll
      for (int ni2 = 0; ni2 < 2; ++ni2)
        hb[ni2] = frag(Hs, wid * 32 + ni2 * 16 + lr, ks, lg);
#pragma unroll
      for (int mi3 = 0; mi3 < 2; ++mi3)
#pragma unroll
        for (int ni2 = 0; ni2 < 2; ++ni2)
          c2a[mi3][ni2] = mfma16(am[mi3][ks], hb[ni2], c2a[mi3][ni2]);
    }
#pragma unroll
    for (int mi3 = 0; mi3 < 2; ++mi3)
#pragma unroll
      for (int ni2 = 0; ni2 < 2; ++ni2) {
        const int hg = col0 + wid * 32 + ni2 * 16 + lr;
#pragma unroll
        for (int r = 0; r < 4; ++r) {
          const int np = mi3 * 16 + lg * 4 + r;
          C2[((size_t)(bg0 + b) * 32 + np) * (size_t)HDIM + hg] =
              (bf16_t)c2a[mi3][ni2][r];
        }
      }
    // stage next batch's G slice (Gs readers done at last barrier)
    if (b < 3) {
      const int bn = b + 1;
      if ((wid >> 1) == (bn >> 1)) {
#pragma unroll
        for (int mil = 0; mil < 2; ++mil) {
          const int mi = (bn & 1) * 2 + mil;
          const int n0 = mil * 16 + lg * 4;
#pragma unroll
          for (int ni = 0; ni < 4; ++ni) {
            const int h = wc + ni * 16 + lr;
            bf16x4 pk;
#pragma unroll
            for (int r = 0; r < 4; ++r) pk[r] = (bf16_t)acc[mi][ni][r];
            *(bf16x4*)(Gs + h * 64 + ((n0 * 2) ^ ((h & 3) << 4))) = pk;
          }
        }
      }
    }
    __syncthreads();
  }
}

// ---------------------------------------------------------------------------
// Kernel B (coef_back): Bc' = C2@W2^T + a2s[n]*b2[d] + (n==0)*y0[b][d].
// 128x128 tile, BK=64, 4 waves x 64x64, 3-slot LDS pipeline (96KB),
// counted vmcnt(8), ONE barrier per K-tile.  grid 256 = 1 block/CU.
// ---------------------------------------------------------------------------
__global__ __launch_bounds__(256) void coef_back(
    const bf16_t* __restrict__ C2, const bf16_t* __restrict__ W2t,
    const float* __restrict__ b2, const float* __restrict__ a2s,
    const float* __restrict__ y0, bf16_t* __restrict__ Bc) {
  __shared__ alignas(16) char lds[98304];  // 3 x (A 16KB + B 16KB)

  const int tid = threadIdx.x;
  const int wid = tid >> 6, lane = tid & 63;
  const int lr = lane & 15, lg = lane >> 4;
  const int id = blockIdx.x;
  const int swz = (id & 7) * 32 + (id >> 3);  // 256 blocks, bijective
  const int bx = swz & 3, by = swz >> 2;      // 4 col-blocks, 64 row-blocks
  const int row0 = by * 128, col0 = bx * 128;
  const int wr = (wid >> 1) * 64, wc = (wid & 1) * 64;

  const bf16_t* Ag = C2 + (size_t)row0 * HDIM;
  const bf16_t* Bg = W2t + (size_t)col0 * HDIM;

  constexpr int nk = HDIM / 64;  // 32
  // prologue: stage tiles 0,1
#pragma unroll
  for (int j = 0; j < 4; ++j) stage256(Ag, HDIM, lds, tid, j);
#pragma unroll
  for (int j = 0; j < 4; ++j) stage256(Bg, HDIM, lds + 16384, tid, j);
#pragma unroll
  for (int j = 0; j < 4; ++j) stage256(Ag + 64, HDIM, lds + 32768, tid, j);
#pragma unroll
  for (int j = 0; j < 4; ++j)
    stage256(Bg + 64, HDIM, lds + 32768 + 16384, tid, j);
  asm volatile("s_waitcnt vmcnt(8)" ::: "memory");  // tile 0 landed
  __builtin_amdgcn_s_barrier();

  const f32x4 fz = {0.f, 0.f, 0.f, 0.f};
  f32x4 acc[4][4];
#pragma unroll
  for (int i = 0; i < 4; ++i)
#pragma unroll
    for (int j = 0; j < 4; ++j) acc[i][j] = fz;

  for (int kt = 0; kt < nk; ++kt) {
    const char* Ab = lds + (kt % 3) * 32768;
    const char* Bb = Ab + 16384;
    if (kt + 2 < nk) {
      char* A2 = lds + ((kt + 2) % 3) * 32768;
      const bf16_t* gA2 = Ag + (size_t)(kt + 2) * 64;
      const bf16_t* gB2 = Bg + (size_t)(kt + 2) * 64;
#pragma unroll
      for (int j = 0; j < 4; ++j) stage256(gA2, HDIM, A2, tid, j);
#pragma unroll
      for (int j = 0; j < 4; ++j) stage256(gB2, HDIM, A2 + 16384, tid, j);
    }
    __builtin_amdgcn_sched_barrier(0);
#pragma unroll
    for (int ks = 0; ks < 2; ++ks) {
      bf16x8 af[4], bfv[4];
#pragma unroll
      for (int mi = 0; mi < 4; ++mi) af[mi] = frag(Ab, wr + mi * 16 + lr, ks, lg);
#pragma unroll
      for (int ni = 0; ni < 4; ++ni) bfv[ni] = frag(Bb, wc + ni * 16 + lr, ks, lg);
#pragma unroll
      for (int mi = 0; mi < 4; ++mi)
#pragma unroll
        for (int ni = 0; ni < 4; ++ni)
          acc[mi][ni] = mfma16(af[mi], bfv[ni], acc[mi][ni]);
    }
    __builtin_amdgcn_sched_barrier(0);
    // wait: next tile (kt+1) fully landed; kt+2's 8 loads may stay in flight
    if (kt + 2 < nk) {
      asm volatile("s_waitcnt vmcnt(8)" ::: "memory");
    } else if (kt + 1 < nk) {
      asm volatile("s_waitcnt vmcnt(0)" ::: "memory");
    }
    __builtin_amdgcn_s_barrier();
  }

#pragma unroll
  for (int ni = 0; ni < 4; ++ni) {
    const int d = col0 + wc + ni * 16 + lr;
    const float b2v = b2[d];
#pragma unroll
    for (int mi = 0; mi < 4; ++mi) {
      const int rl = row0 + wr + mi * 16 + lg * 4;
#pragma unroll
      for (int r = 0; r < 4; ++r) {
        const int row = rl + r;
        const int np = row & 31, b = row >> 5;
        float v = acc[mi][ni][r] + a2s[np] * b2v;
        if (np == 0) v += y0[(size_t)b * DDIM + d];
        Bc[(size_t)row * DDIM + d] = (bf16_t)v;
      }
    }
  }
}

// traj[p,b,d] = sum_n PS[p][n] * Bc[b*32+n][d]
__global__ __launch_bounds__(256) void traj_eval(
    const bf16_t* __restrict__ Bc, const float* __restrict__ PS,
    float* __restrict__ out) {
  __shared__ bf16_t Bsh[NC * 128];
  const int b = blockIdx.x >> 2, d0 = (blockIdx.x & 3) * 128;
#pragma unroll
  for (int j = 0; j < 2; ++j) {
    const int t = j * 256 + threadIdx.x;
    const int n = t >> 4, dd = (t & 15) * 8;
    *(bf16x8*)(Bsh + n * 128 + dd) =
        *(const bf16x8*)(Bc + ((size_t)b * 32 + n) * DDIM + d0 + dd);
  }
  __syncthreads();
  for (int o = threadIdx.x; o < PT * 128; o += 256) {
    const int p = o >> 7, d = o & 127;
    float s = 0.f;
#pragma unroll
    for (int n = 0; n < NC; ++n) s += PS[p * 32 + n] * (float)Bsh[n * 128 + d];
    out[(size_t)p * BATCH * DDIM + (size_t)b * DDIM + d0 + d] = s;
  }
}

// ---------------------------------------------------------------------------
extern "C" void kernel_launch(void* const* d_in, const int* in_sizes, int n_in,
                              void* d_out, int out_size, void* d_ws,
                              size_t ws_size, hipStream_t stream) {
  (void)in_sizes; (void)n_in; (void)out_size;
  const float* y0 = (const float*)d_in[0];
  const float* tspan = (const float*)d_in[1];
  const float* W1 = (const float*)d_in[2];
  const float* b1 = (const float*)d_in[3];
  const float* W2 = (const float*)d_in[4];
  const float* b2 = (const float*)d_in[5];
  float* out = (float*)d_out;

  char* ws = (char*)d_ws;
  const size_t szW1t = (size_t)HDIM * DDIM * 2;
  const size_t szW2t = (size_t)DDIM * HDIM * 2;
  const size_t szPhiT = 64 * 32 * 2;
  const size_t szM2 = 32 * 64 * 2;
  const size_t szPS = 16 * 32 * 4;
  const size_t szA2s = 256;
  const size_t szBc = (size_t)CROWS * DDIM * 2;
  const size_t szC2 = (size_t)CROWS * HDIM * 2;
  if (ws_size < szW1t + szW2t + szPhiT + szM2 + szPS + szA2s + szBc + szC2)
    return;

  bf16_t* W1t = (bf16_t*)ws; ws += szW1t;
  bf16_t* W2t = (bf16_t*)ws; ws += szW2t;
  bf16_t* PhiT = (bf16_t*)ws; ws += szPhiT;
  bf16_t* M2 = (bf16_t*)ws; ws += szM2;
  float* PS = (float*)ws; ws += szPS;
  float* a2s = (float*)ws; ws += szA2s;
  bf16_t* Bc = (bf16_t*)ws; ws += szBc;
  bf16_t* C2 = (bf16_t*)ws; ws += szC2;

  prep_matrices<<<1, 256, 0, stream>>>(tspan, PhiT, M2, PS, a2s);
  transpose_bf16<<<dim3(HDIM / 32, DDIM / 32), dim3(32, 8), 0, stream>>>(
      W1, W1t, DDIM, HDIM);
  transpose_bf16<<<dim3(DDIM / 32, HDIM / 32), dim3(32, 8), 0, stream>>>(
      W2, W2t, HDIM, DDIM);
  init_Bc<<<(CROWS * DDIM) / 256, 256, 0, stream>>>(y0, Bc);

  for (int it = 0; it < NITER; ++it) {
    mlp_front<<<1024, 256, 0, stream>>>(Bc, W1t, b1, PhiT, M2, C2);
    coef_back<<<256, 256, 0, stream>>>(C2, W2t, b2, a2s, y0, Bc);
  }
  traj_eval<<<BATCH * 4, 256, 0, stream>>>(Bc, PS, out);
}